// Round 1
// baseline (362.846 us; speedup 1.0000x reference)
//
#include <hip/hip_runtime.h>
#include <hip/hip_bf16.h>

// ---------------------------------------------------------------------------
// Transformer block, B=8 S=1024 H=768 NH=12 HD=64 I=3072.  fp32 in/out,
// bf16 MFMA internals.  Round 0: correctness-first, m97-class GEMM skeleton.
// ---------------------------------------------------------------------------

typedef __attribute__((ext_vector_type(8))) short bf16x8;
typedef __attribute__((ext_vector_type(4))) float f32x4;

#define MFMA16(a, b, c) __builtin_amdgcn_mfma_f32_16x16x32_bf16((a), (b), (c), 0, 0, 0)

__device__ inline short f2bf(float x) {
    __hip_bfloat16 h = __float2bfloat16(x);
    return *reinterpret_cast<short*>(&h);
}

__device__ inline void gload_lds16(const void* g, void* lds) {
    __builtin_amdgcn_global_load_lds(
        (const __attribute__((address_space(1))) unsigned int*)g,
        (__attribute__((address_space(3))) unsigned int*)lds,
        16, 0, 0);
}

// ---------------------------------------------------------------------------
// Weight prep: W fp32 [K,N] -> Wt bf16 [N,K]   (tiled transpose + cast)
// ---------------------------------------------------------------------------
__global__ __launch_bounds__(256) void transpose_w(
    const float* __restrict__ W, short* __restrict__ Wt, int K, int N) {
    __shared__ float tile[32][33];
    const int tx = threadIdx.x & 31, ty = threadIdx.x >> 5;  // ty 0..7
    const int n0 = blockIdx.x * 32, k0 = blockIdx.y * 32;
#pragma unroll
    for (int i = 0; i < 4; ++i)
        tile[ty + i * 8][tx] = W[(size_t)(k0 + ty + i * 8) * N + n0 + tx];
    __syncthreads();
#pragma unroll
    for (int i = 0; i < 4; ++i)
        Wt[(size_t)(n0 + ty + i * 8) * K + k0 + tx] = f2bf(tile[tx][ty + i * 8]);
}

// ---------------------------------------------------------------------------
// LayerNorm: fp32 [M,768] -> bf16 [M,768]   (one block per row)
// ---------------------------------------------------------------------------
__global__ __launch_bounds__(256) void ln_k(
    const float* __restrict__ x, const float* __restrict__ g,
    const float* __restrict__ b, short* __restrict__ out) {
    const int row = blockIdx.x;
    const int tid = threadIdx.x;
    const float* xr = x + (size_t)row * 768;
    float v[3];
    float s = 0.f, sq = 0.f;
#pragma unroll
    for (int i = 0; i < 3; ++i) {
        v[i] = xr[tid + i * 256];
        s += v[i];
        sq += v[i] * v[i];
    }
#pragma unroll
    for (int off = 32; off >= 1; off >>= 1) {
        s += __shfl_xor(s, off);
        sq += __shfl_xor(sq, off);
    }
    __shared__ float ss[4], ssq[4];
    const int wid = tid >> 6;
    if ((tid & 63) == 0) { ss[wid] = s; ssq[wid] = sq; }
    __syncthreads();
    s = ss[0] + ss[1] + ss[2] + ss[3];
    sq = ssq[0] + ssq[1] + ssq[2] + ssq[3];
    const float mean = s * (1.0f / 768.0f);
    const float var = sq * (1.0f / 768.0f) - mean * mean;  // biased
    const float rstd = rsqrtf(var + 1e-5f);
    short* outr = out + (size_t)row * 768;
#pragma unroll
    for (int i = 0; i < 3; ++i) {
        const int c = tid + i * 256;
        outr[c] = f2bf((v[i] - mean) * rstd * g[c] + b[c]);
    }
}

// ---------------------------------------------------------------------------
// GEMM:  C[M,N] = A[M,K](bf16) @ Wt[N,K]^T(bf16) + bias, fused epilogues.
// 128x128 tile, BK=32, 256 thr = 4 waves (2x2), each wave 64x64 (4x4 frags).
// m97 pattern: global_load_lds width-16 staging, linear LDS, 2 barriers/K.
// ---------------------------------------------------------------------------
enum { MODE_BF16 = 0, MODE_QKV = 1, MODE_F32RES = 2, MODE_GELU = 3 };

template <int MODE>
__global__ __launch_bounds__(256) void gemm_k(
    const short* __restrict__ A, const short* __restrict__ Wt,
    const float* __restrict__ bias, const float* __restrict__ resid,
    float* __restrict__ outf, short* __restrict__ outh,
    short* __restrict__ Qo, short* __restrict__ Ko, short* __restrict__ Vto,
    int M, int N, int K) {
    __shared__ __attribute__((aligned(128))) short Al[128 * 32];
    __shared__ __attribute__((aligned(128))) short Bl[128 * 32];
    const int tid = threadIdx.x;
    const int lane = tid & 63;
    const int w = tid >> 6;
    const int wm = w >> 1, wn = w & 1;
    const int m0 = blockIdx.x * 128, n0 = blockIdx.y * 128;

    f32x4 acc[4][4] = {};

    const int lr = lane >> 2;            // row-within-16-chunk
    const int lc = (lane & 3) * 8;       // 8-elem column part
    const int ca = w * 2;                // this wave's chunks: ca, ca+1

    for (int k0 = 0; k0 < K; k0 += 32) {
#pragma unroll
        for (int i = 0; i < 2; ++i) {
            const int ch = ca + i;
            gload_lds16(A + (size_t)(m0 + ch * 16 + lr) * K + k0 + lc, &Al[ch * 512]);
            gload_lds16(Wt + (size_t)(n0 + ch * 16 + lr) * K + k0 + lc, &Bl[ch * 512]);
        }
        __syncthreads();  // drains vmcnt before barrier
        bf16x8 av[4], bv[4];
#pragma unroll
        for (int mi = 0; mi < 4; ++mi)
            av[mi] = *(const bf16x8*)&Al[(wm * 64 + mi * 16 + (lane & 15)) * 32 + (lane >> 4) * 8];
#pragma unroll
        for (int ni = 0; ni < 4; ++ni)
            bv[ni] = *(const bf16x8*)&Bl[(wn * 64 + ni * 16 + (lane & 15)) * 32 + (lane >> 4) * 8];
#pragma unroll
        for (int mi = 0; mi < 4; ++mi)
#pragma unroll
            for (int ni = 0; ni < 4; ++ni)
                acc[mi][ni] = MFMA16(av[mi], bv[ni], acc[mi][ni]);
        __syncthreads();
    }

    // Epilogue.  C/D frag layout: col = lane&15, row = (lane>>4)*4 + r.
#pragma unroll
    for (int mi = 0; mi < 4; ++mi) {
#pragma unroll
        for (int ni = 0; ni < 4; ++ni) {
#pragma unroll
            for (int r = 0; r < 4; ++r) {
                const int row = m0 + wm * 64 + mi * 16 + (lane >> 4) * 4 + r;
                const int col = n0 + wn * 64 + ni * 16 + (lane & 15);
                float v = acc[mi][ni][r] + bias[col];
                if constexpr (MODE == MODE_BF16) {
                    outh[(size_t)row * N + col] = f2bf(v);
                } else if constexpr (MODE == MODE_GELU) {
                    const float t = v + 0.044715f * v * v * v;
                    const float gl = 0.5f * v * (1.0f + tanhf(0.7978845608028654f * t));
                    outh[(size_t)row * N + col] = f2bf(gl);
                } else if constexpr (MODE == MODE_F32RES) {
                    outf[(size_t)row * N + col] = v + resid[(size_t)row * N + col];
                } else {  // MODE_QKV: scatter into Q[B,NH,S,HD], K[B,NH,S,HD], Vt[B,NH,HD,S]
                    const int bb = row >> 10, s = row & 1023;
                    if (col < 768) {
                        const int hh = col >> 6, d = col & 63;
                        Qo[(((size_t)(bb * 12 + hh)) * 1024 + s) * 64 + d] = f2bf(v);
                    } else if (col < 1536) {
                        const int c2 = col - 768;
                        const int hh = c2 >> 6, d = c2 & 63;
                        Ko[(((size_t)(bb * 12 + hh)) * 1024 + s) * 64 + d] = f2bf(v);
                    } else {
                        const int c2 = col - 1536;
                        const int hh = c2 >> 6, d = c2 & 63;
                        Vto[(((size_t)(bb * 12 + hh)) * 64 + d) * 1024 + s] = f2bf(v);
                    }
                }
            }
        }
    }
}

// ---------------------------------------------------------------------------
// Flash attention.  Grid: B*NH*16 blocks; block = 4 waves, wave = 16 q-rows.
// K/V tiles (64 kv) staged in LDS (stride 80 shorts: 16B-aligned, 4-way max
// bank aliasing).  P goes through per-wave LDS to reach A-fragment layout.
// ---------------------------------------------------------------------------
__global__ __launch_bounds__(256) void attn_k(
    const short* __restrict__ Q, const short* __restrict__ Kg,
    const short* __restrict__ Vtg, short* __restrict__ out) {
    __shared__ __attribute__((aligned(128))) short Kl[64 * 80];
    __shared__ __attribute__((aligned(128))) short Vl[64 * 80];
    __shared__ __attribute__((aligned(128))) short Pl[4][16 * 80];
    const int tid = threadIdx.x, lane = tid & 63, w = tid >> 6;
    const int bid = blockIdx.x;
    const int qt = bid & 15, bh = bid >> 4;
    const int b = bh / 12, h = bh % 12;
    const int q0 = qt * 64 + w * 16;

    // Q fragments (A-operand: row = lane&15, k = (lane>>4)*8 + j, two 32-d halves)
    bf16x8 aq[2];
    const short* Qb = Q + ((size_t)bh * 1024 + q0) * 64;
#pragma unroll
    for (int kk = 0; kk < 2; ++kk)
        aq[kk] = *(const bf16x8*)&Qb[(size_t)(lane & 15) * 64 + kk * 32 + (lane >> 4) * 8];

    float m_run[4], l_run[4];
    f32x4 o[4] = {};
#pragma unroll
    for (int r = 0; r < 4; ++r) { m_run[r] = -1e30f; l_run[r] = 0.f; }

    const short* Kb = Kg + (size_t)bh * 1024 * 64;
    const short* Vb = Vtg + (size_t)bh * 64 * 1024;

    for (int kv0 = 0; kv0 < 1024; kv0 += 64) {
        for (int c = tid; c < 512; c += 256) {
            const int rr = c >> 3, pp = (c & 7) * 8;
            *(bf16x8*)&Kl[rr * 80 + pp] = *(const bf16x8*)&Kb[(size_t)(kv0 + rr) * 64 + pp];
            *(bf16x8*)&Vl[rr * 80 + pp] = *(const bf16x8*)&Vb[(size_t)rr * 1024 + kv0 + pp];
        }
        __syncthreads();

        // scores: 16 q-rows x 64 kv
        f32x4 sc[4];
#pragma unroll
        for (int nk = 0; nk < 4; ++nk) {
            const bf16x8 kb0 = *(const bf16x8*)&Kl[(nk * 16 + (lane & 15)) * 80 + (lane >> 4) * 8];
            const bf16x8 kb1 = *(const bf16x8*)&Kl[(nk * 16 + (lane & 15)) * 80 + 32 + (lane >> 4) * 8];
            f32x4 z = {};
            z = MFMA16(aq[0], kb0, z);
            z = MFMA16(aq[1], kb1, z);
            sc[nk] = z * 0.125f;  // 1/sqrt(64)
        }

        // online softmax (row = (lane>>4)*4 + r; 16 cols across lanes 0..15 of group)
        float alpha[4], padd[4][4];
#pragma unroll
        for (int r = 0; r < 4; ++r) {
            float ml = fmaxf(fmaxf(sc[0][r], sc[1][r]), fmaxf(sc[2][r], sc[3][r]));
#pragma unroll
            for (int mk = 1; mk <= 8; mk <<= 1) ml = fmaxf(ml, __shfl_xor(ml, mk));
            const float mn = fmaxf(m_run[r], ml);
            alpha[r] = __expf(m_run[r] - mn);
            m_run[r] = mn;
            float rsum = 0.f;
#pragma unroll
            for (int nk = 0; nk < 4; ++nk) {
                padd[nk][r] = __expf(sc[nk][r] - mn);
                rsum += padd[nk][r];
            }
#pragma unroll
            for (int mk = 1; mk <= 8; mk <<= 1) rsum += __shfl_xor(rsum, mk);
            l_run[r] = l_run[r] * alpha[r] + rsum;
#pragma unroll
            for (int dn = 0; dn < 4; ++dn) o[dn][r] *= alpha[r];
        }

        // P (C-layout) -> LDS -> A-layout fragments
#pragma unroll
        for (int nk = 0; nk < 4; ++nk)
#pragma unroll
            for (int r = 0; r < 4; ++r)
                Pl[w][((lane >> 4) * 4 + r) * 80 + nk * 16 + (lane & 15)] = f2bf(padd[nk][r]);
        bf16x8 pa[2];
#pragma unroll
        for (int kk = 0; kk < 2; ++kk)
            pa[kk] = *(const bf16x8*)&Pl[w][(lane & 15) * 80 + kk * 32 + (lane >> 4) * 8];

        // PV: o[16 x 64d] += P[16 x 64kv] @ V[64kv x 64d]
#pragma unroll
        for (int dn = 0; dn < 4; ++dn) {
            const bf16x8 bv0 = *(const bf16x8*)&Vl[(dn * 16 + (lane & 15)) * 80 + (lane >> 4) * 8];
            const bf16x8 bv1 = *(const bf16x8*)&Vl[(dn * 16 + (lane & 15)) * 80 + 32 + (lane >> 4) * 8];
            o[dn] = MFMA16(pa[0], bv0, o[dn]);
            o[dn] = MFMA16(pa[1], bv1, o[dn]);
        }
        __syncthreads();
    }

    // normalize + write attn output as [B,S,H] bf16
#pragma unroll
    for (int dn = 0; dn < 4; ++dn)
#pragma unroll
        for (int r = 0; r < 4; ++r) {
            const int srow = q0 + (lane >> 4) * 4 + r;
            const float v = o[dn][r] / l_run[r];
            out[((size_t)(b * 1024) + srow) * 768 + h * 64 + dn * 16 + (lane & 15)] = f2bf(v);
        }
}

// ---------------------------------------------------------------------------
// Launch
// ---------------------------------------------------------------------------
extern "C" void kernel_launch(void* const* d_in, const int* in_sizes, int n_in,
                              void* d_out, int out_size, void* d_ws, size_t ws_size,
                              hipStream_t stream) {
    const float* x      = (const float*)d_in[0];
    const float* ln1_g  = (const float*)d_in[1];
    const float* ln1_b  = (const float*)d_in[2];
    const float* qkv_w  = (const float*)d_in[3];
    const float* qkv_b  = (const float*)d_in[4];
    const float* proj_w = (const float*)d_in[5];
    const float* proj_b = (const float*)d_in[6];
    const float* ln2_g  = (const float*)d_in[7];
    const float* ln2_b  = (const float*)d_in[8];
    const float* fc1_w  = (const float*)d_in[9];
    const float* fc1_b  = (const float*)d_in[10];
    const float* fc2_w  = (const float*)d_in[11];
    const float* fc2_b  = (const float*)d_in[12];
    float* outp = (float*)d_out;

    char* ws = (char*)d_ws;
    size_t off = 0;
    auto alloc = [&](size_t bytes) {
        char* p = ws + off;
        off = (off + bytes + 255) & ~(size_t)255;
        return p;
    };
    short* wt_qkv  = (short*)alloc(2304ull * 768 * 2);
    short* wt_proj = (short*)alloc(768ull * 768 * 2);
    short* wt_fc1  = (short*)alloc(3072ull * 768 * 2);
    short* wt_fc2  = (short*)alloc(768ull * 3072 * 2);
    short* hbuf    = (short*)alloc(8192ull * 768 * 2);
    short* Qb      = (short*)alloc(8192ull * 768 * 2);   // [B,NH,S,HD]
    short* Kbuf    = (short*)alloc(8192ull * 768 * 2);   // [B,NH,S,HD]
    short* Vtb     = (short*)alloc(8192ull * 768 * 2);   // [B,NH,HD,S]
    short* attnb   = (short*)alloc(8192ull * 768 * 2);   // [B,S,H]
    float* x2      = (float*)alloc(8192ull * 768 * 4);   // fp32 residual stream
    short* mfc     = Qb;  // alias: fc1 output [8192,3072] over dead Q/K/Vt/attn
    (void)ws_size; (void)in_sizes; (void)n_in; (void)out_size;

    // weight prep
    transpose_w<<<dim3(2304 / 32, 768 / 32), 256, 0, stream>>>(qkv_w, wt_qkv, 768, 2304);
    transpose_w<<<dim3(768 / 32, 768 / 32), 256, 0, stream>>>(proj_w, wt_proj, 768, 768);
    transpose_w<<<dim3(3072 / 32, 768 / 32), 256, 0, stream>>>(fc1_w, wt_fc1, 768, 3072);
    transpose_w<<<dim3(768 / 32, 3072 / 32), 256, 0, stream>>>(fc2_w, wt_fc2, 3072, 768);

    // attention sublayer
    ln_k<<<8192, 256, 0, stream>>>(x, ln1_g, ln1_b, hbuf);
    gemm_k<MODE_QKV><<<dim3(64, 18), 256, 0, stream>>>(
        hbuf, wt_qkv, qkv_b, nullptr, nullptr, nullptr, Qb, Kbuf, Vtb, 8192, 2304, 768);
    attn_k<<<1536, 256, 0, stream>>>(Qb, Kbuf, Vtb, attnb);
    gemm_k<MODE_F32RES><<<dim3(64, 6), 256, 0, stream>>>(
        attnb, wt_proj, proj_b, x, x2, nullptr, nullptr, nullptr, nullptr, 8192, 768, 768);

    // MLP sublayer
    ln_k<<<8192, 256, 0, stream>>>(x2, ln2_g, ln2_b, hbuf);
    gemm_k<MODE_GELU><<<dim3(64, 24), 256, 0, stream>>>(
        hbuf, wt_fc1, fc1_b, nullptr, nullptr, mfc, nullptr, nullptr, nullptr, 8192, 3072, 768);
    gemm_k<MODE_F32RES><<<dim3(64, 6), 256, 0, stream>>>(
        mfc, wt_fc2, fc2_b, x2, outp, nullptr, nullptr, nullptr, nullptr, 8192, 768, 3072);
}

// Round 2
// 344.403 us; speedup vs baseline: 1.0535x; 1.0535x over previous
//
#include <hip/hip_runtime.h>
#include <hip/hip_bf16.h>

// ---------------------------------------------------------------------------
// Transformer block, B=8 S=1024 H=768 NH=12 HD=64 I=3072.  fp32 in/out,
// bf16 MFMA internals.
// Round 1: GEMM -> double-buffered 2-phase pipeline (T3-minimum recipe):
// stage(t+1) issued before compute(t), single __syncthreads per K-step.
// ---------------------------------------------------------------------------

typedef __attribute__((ext_vector_type(8))) short bf16x8;
typedef __attribute__((ext_vector_type(4))) float f32x4;

#define MFMA16(a, b, c) __builtin_amdgcn_mfma_f32_16x16x32_bf16((a), (b), (c), 0, 0, 0)

__device__ inline short f2bf(float x) {
    __hip_bfloat16 h = __float2bfloat16(x);
    return *reinterpret_cast<short*>(&h);
}

__device__ inline void gload_lds16(const void* g, void* lds) {
    __builtin_amdgcn_global_load_lds(
        (const __attribute__((address_space(1))) unsigned int*)g,
        (__attribute__((address_space(3))) unsigned int*)lds,
        16, 0, 0);
}

// ---------------------------------------------------------------------------
// Weight prep: W fp32 [K,N] -> Wt bf16 [N,K]   (tiled transpose + cast)
// ---------------------------------------------------------------------------
__global__ __launch_bounds__(256) void transpose_w(
    const float* __restrict__ W, short* __restrict__ Wt, int K, int N) {
    __shared__ float tile[32][33];
    const int tx = threadIdx.x & 31, ty = threadIdx.x >> 5;  // ty 0..7
    const int n0 = blockIdx.x * 32, k0 = blockIdx.y * 32;
#pragma unroll
    for (int i = 0; i < 4; ++i)
        tile[ty + i * 8][tx] = W[(size_t)(k0 + ty + i * 8) * N + n0 + tx];
    __syncthreads();
#pragma unroll
    for (int i = 0; i < 4; ++i)
        Wt[(size_t)(n0 + ty + i * 8) * K + k0 + tx] = f2bf(tile[tx][ty + i * 8]);
}

// ---------------------------------------------------------------------------
// LayerNorm: fp32 [M,768] -> bf16 [M,768]   (one block per row)
// ---------------------------------------------------------------------------
__global__ __launch_bounds__(256) void ln_k(
    const float* __restrict__ x, const float* __restrict__ g,
    const float* __restrict__ b, short* __restrict__ out) {
    const int row = blockIdx.x;
    const int tid = threadIdx.x;
    const float* xr = x + (size_t)row * 768;
    float v[3];
    float s = 0.f, sq = 0.f;
#pragma unroll
    for (int i = 0; i < 3; ++i) {
        v[i] = xr[tid + i * 256];
        s += v[i];
        sq += v[i] * v[i];
    }
#pragma unroll
    for (int off = 32; off >= 1; off >>= 1) {
        s += __shfl_xor(s, off);
        sq += __shfl_xor(sq, off);
    }
    __shared__ float ss[4], ssq[4];
    const int wid = tid >> 6;
    if ((tid & 63) == 0) { ss[wid] = s; ssq[wid] = sq; }
    __syncthreads();
    s = ss[0] + ss[1] + ss[2] + ss[3];
    sq = ssq[0] + ssq[1] + ssq[2] + ssq[3];
    const float mean = s * (1.0f / 768.0f);
    const float var = sq * (1.0f / 768.0f) - mean * mean;  // biased
    const float rstd = rsqrtf(var + 1e-5f);
    short* outr = out + (size_t)row * 768;
#pragma unroll
    for (int i = 0; i < 3; ++i) {
        const int c = tid + i * 256;
        outr[c] = f2bf((v[i] - mean) * rstd * g[c] + b[c]);
    }
}

// ---------------------------------------------------------------------------
// GEMM:  C[M,N] = A[M,K](bf16) @ Wt[N,K]^T(bf16) + bias, fused epilogues.
// 128x128 tile, BK=32, 256 thr = 4 waves (2x2), each wave 64x64 (4x4 frags).
// Double-buffered 2-phase: STAGE(buf^1, t+1) issued BEFORE compute on buf.
// __syncthreads() per K-step supplies the vmcnt(0)+lgkmcnt(0) drain.
// ---------------------------------------------------------------------------
enum { MODE_BF16 = 0, MODE_QKV = 1, MODE_F32RES = 2, MODE_GELU = 3 };

template <int MODE>
__global__ __launch_bounds__(256) void gemm_k(
    const short* __restrict__ A, const short* __restrict__ Wt,
    const float* __restrict__ bias, const float* __restrict__ resid,
    float* __restrict__ outf, short* __restrict__ outh,
    short* __restrict__ Qo, short* __restrict__ Ko, short* __restrict__ Vto,
    int M, int N, int K) {
    __shared__ __attribute__((aligned(128))) short Al[2][128 * 32];
    __shared__ __attribute__((aligned(128))) short Bl[2][128 * 32];
    const int tid = threadIdx.x;
    const int lane = tid & 63;
    const int w = tid >> 6;
    const int wm = w >> 1, wn = w & 1;
    const int m0 = blockIdx.x * 128, n0 = blockIdx.y * 128;

    f32x4 acc[4][4] = {};

    const int lr = lane >> 2;            // row-within-16-chunk
    const int lc = (lane & 3) * 8;       // 8-elem column part
    const int ca = w * 2;                // this wave's chunks: ca, ca+1

    const short* Arow0 = A + (size_t)(m0 + ca * 16 + lr) * K + lc;
    const short* Arow1 = A + (size_t)(m0 + (ca + 1) * 16 + lr) * K + lc;
    const short* Brow0 = Wt + (size_t)(n0 + ca * 16 + lr) * K + lc;
    const short* Brow1 = Wt + (size_t)(n0 + (ca + 1) * 16 + lr) * K + lc;

    auto stage = [&](int buf, int k0) {
        gload_lds16(Arow0 + k0, &Al[buf][ca * 512]);
        gload_lds16(Brow0 + k0, &Bl[buf][ca * 512]);
        gload_lds16(Arow1 + k0, &Al[buf][(ca + 1) * 512]);
        gload_lds16(Brow1 + k0, &Bl[buf][(ca + 1) * 512]);
    };

    stage(0, 0);
    __syncthreads();  // drains vmcnt(0) before barrier

    const int nt = K >> 5;
    int cur = 0;
    for (int t = 0; t < nt; ++t) {
        if (t + 1 < nt) stage(cur ^ 1, (t + 1) << 5);  // prefetch next K-tile
        bf16x8 av[4], bv[4];
#pragma unroll
        for (int mi = 0; mi < 4; ++mi)
            av[mi] = *(const bf16x8*)&Al[cur][(wm * 64 + mi * 16 + (lane & 15)) * 32 + (lane >> 4) * 8];
#pragma unroll
        for (int ni = 0; ni < 4; ++ni)
            bv[ni] = *(const bf16x8*)&Bl[cur][(wn * 64 + ni * 16 + (lane & 15)) * 32 + (lane >> 4) * 8];
#pragma unroll
        for (int mi = 0; mi < 4; ++mi)
#pragma unroll
            for (int ni = 0; ni < 4; ++ni)
                acc[mi][ni] = MFMA16(av[mi], bv[ni], acc[mi][ni]);
        __syncthreads();  // vmcnt(0): staged loads landed; lgkm: reads done
        cur ^= 1;
    }

    // Epilogue.  C/D frag layout: col = lane&15, row = (lane>>4)*4 + r.
#pragma unroll
    for (int mi = 0; mi < 4; ++mi) {
#pragma unroll
        for (int ni = 0; ni < 4; ++ni) {
#pragma unroll
            for (int r = 0; r < 4; ++r) {
                const int row = m0 + wm * 64 + mi * 16 + (lane >> 4) * 4 + r;
                const int col = n0 + wn * 64 + ni * 16 + (lane & 15);
                float v = acc[mi][ni][r] + bias[col];
                if constexpr (MODE == MODE_BF16) {
                    outh[(size_t)row * N + col] = f2bf(v);
                } else if constexpr (MODE == MODE_GELU) {
                    const float t = v + 0.044715f * v * v * v;
                    const float gl = 0.5f * v * (1.0f + tanhf(0.7978845608028654f * t));
                    outh[(size_t)row * N + col] = f2bf(gl);
                } else if constexpr (MODE == MODE_F32RES) {
                    outf[(size_t)row * N + col] = v + resid[(size_t)row * N + col];
                } else {  // MODE_QKV: scatter into Q[B,NH,S,HD], K[B,NH,S,HD], Vt[B,NH,HD,S]
                    const int bb = row >> 10, s = row & 1023;
                    if (col < 768) {
                        const int hh = col >> 6, d = col & 63;
                        Qo[(((size_t)(bb * 12 + hh)) * 1024 + s) * 64 + d] = f2bf(v);
                    } else if (col < 1536) {
                        const int c2 = col - 768;
                        const int hh = c2 >> 6, d = c2 & 63;
                        Ko[(((size_t)(bb * 12 + hh)) * 1024 + s) * 64 + d] = f2bf(v);
                    } else {
                        const int c2 = col - 1536;
                        const int hh = c2 >> 6, d = c2 & 63;
                        Vto[(((size_t)(bb * 12 + hh)) * 64 + d) * 1024 + s] = f2bf(v);
                    }
                }
            }
        }
    }
}

// ---------------------------------------------------------------------------
// Flash attention.  Grid: B*NH*16 blocks; block = 4 waves, wave = 16 q-rows.
// K/V tiles (64 kv) staged in LDS (stride 80 shorts).  P via per-wave LDS.
// ---------------------------------------------------------------------------
__global__ __launch_bounds__(256) void attn_k(
    const short* __restrict__ Q, const short* __restrict__ Kg,
    const short* __restrict__ Vtg, short* __restrict__ out) {
    __shared__ __attribute__((aligned(128))) short Kl[64 * 80];
    __shared__ __attribute__((aligned(128))) short Vl[64 * 80];
    __shared__ __attribute__((aligned(128))) short Pl[4][16 * 80];
    const int tid = threadIdx.x, lane = tid & 63, w = tid >> 6;
    const int bid = blockIdx.x;
    const int qt = bid & 15, bh = bid >> 4;
    const int b = bh / 12, h = bh % 12;
    const int q0 = qt * 64 + w * 16;

    bf16x8 aq[2];
    const short* Qb = Q + ((size_t)bh * 1024 + q0) * 64;
#pragma unroll
    for (int kk = 0; kk < 2; ++kk)
        aq[kk] = *(const bf16x8*)&Qb[(size_t)(lane & 15) * 64 + kk * 32 + (lane >> 4) * 8];

    float m_run[4], l_run[4];
    f32x4 o[4] = {};
#pragma unroll
    for (int r = 0; r < 4; ++r) { m_run[r] = -1e30f; l_run[r] = 0.f; }

    const short* Kb = Kg + (size_t)bh * 1024 * 64;
    const short* Vb = Vtg + (size_t)bh * 64 * 1024;

    for (int kv0 = 0; kv0 < 1024; kv0 += 64) {
        for (int c = tid; c < 512; c += 256) {
            const int rr = c >> 3, pp = (c & 7) * 8;
            *(bf16x8*)&Kl[rr * 80 + pp] = *(const bf16x8*)&Kb[(size_t)(kv0 + rr) * 64 + pp];
            *(bf16x8*)&Vl[rr * 80 + pp] = *(const bf16x8*)&Vb[(size_t)rr * 1024 + kv0 + pp];
        }
        __syncthreads();

        f32x4 sc[4];
#pragma unroll
        for (int nk = 0; nk < 4; ++nk) {
            const bf16x8 kb0 = *(const bf16x8*)&Kl[(nk * 16 + (lane & 15)) * 80 + (lane >> 4) * 8];
            const bf16x8 kb1 = *(const bf16x8*)&Kl[(nk * 16 + (lane & 15)) * 80 + 32 + (lane >> 4) * 8];
            f32x4 z = {};
            z = MFMA16(aq[0], kb0, z);
            z = MFMA16(aq[1], kb1, z);
            sc[nk] = z * 0.125f;  // 1/sqrt(64)
        }

        float alpha[4], padd[4][4];
#pragma unroll
        for (int r = 0; r < 4; ++r) {
            float ml = fmaxf(fmaxf(sc[0][r], sc[1][r]), fmaxf(sc[2][r], sc[3][r]));
#pragma unroll
            for (int mk = 1; mk <= 8; mk <<= 1) ml = fmaxf(ml, __shfl_xor(ml, mk));
            const float mn = fmaxf(m_run[r], ml);
            alpha[r] = __expf(m_run[r] - mn);
            m_run[r] = mn;
            float rsum = 0.f;
#pragma unroll
            for (int nk = 0; nk < 4; ++nk) {
                padd[nk][r] = __expf(sc[nk][r] - mn);
                rsum += padd[nk][r];
            }
#pragma unroll
            for (int mk = 1; mk <= 8; mk <<= 1) rsum += __shfl_xor(rsum, mk);
            l_run[r] = l_run[r] * alpha[r] + rsum;
#pragma unroll
            for (int dn = 0; dn < 4; ++dn) o[dn][r] *= alpha[r];
        }

#pragma unroll
        for (int nk = 0; nk < 4; ++nk)
#pragma unroll
            for (int r = 0; r < 4; ++r)
                Pl[w][((lane >> 4) * 4 + r) * 80 + nk * 16 + (lane & 15)] = f2bf(padd[nk][r]);
        bf16x8 pa[2];
#pragma unroll
        for (int kk = 0; kk < 2; ++kk)
            pa[kk] = *(const bf16x8*)&Pl[w][(lane & 15) * 80 + kk * 32 + (lane >> 4) * 8];

#pragma unroll
        for (int dn = 0; dn < 4; ++dn) {
            const bf16x8 bv0 = *(const bf16x8*)&Vl[(dn * 16 + (lane & 15)) * 80 + (lane >> 4) * 8];
            const bf16x8 bv1 = *(const bf16x8*)&Vl[(dn * 16 + (lane & 15)) * 80 + 32 + (lane >> 4) * 8];
            o[dn] = MFMA16(pa[0], bv0, o[dn]);
            o[dn] = MFMA16(pa[1], bv1, o[dn]);
        }
        __syncthreads();
    }

#pragma unroll
    for (int dn = 0; dn < 4; ++dn)
#pragma unroll
        for (int r = 0; r < 4; ++r) {
            const int srow = q0 + (lane >> 4) * 4 + r;
            const float v = o[dn][r] / l_run[r];
            out[((size_t)(b * 1024) + srow) * 768 + h * 64 + dn * 16 + (lane & 15)] = f2bf(v);
        }
}

// ---------------------------------------------------------------------------
// Launch
// ---------------------------------------------------------------------------
extern "C" void kernel_launch(void* const* d_in, const int* in_sizes, int n_in,
                              void* d_out, int out_size, void* d_ws, size_t ws_size,
                              hipStream_t stream) {
    const float* x      = (const float*)d_in[0];
    const float* ln1_g  = (const float*)d_in[1];
    const float* ln1_b  = (const float*)d_in[2];
    const float* qkv_w  = (const float*)d_in[3];
    const float* qkv_b  = (const float*)d_in[4];
    const float* proj_w = (const float*)d_in[5];
    const float* proj_b = (const float*)d_in[6];
    const float* ln2_g  = (const float*)d_in[7];
    const float* ln2_b  = (const float*)d_in[8];
    const float* fc1_w  = (const float*)d_in[9];
    const float* fc1_b  = (const float*)d_in[10];
    const float* fc2_w  = (const float*)d_in[11];
    const float* fc2_b  = (const float*)d_in[12];
    float* outp = (float*)d_out;

    char* ws = (char*)d_ws;
    size_t off = 0;
    auto alloc = [&](size_t bytes) {
        char* p = ws + off;
        off = (off + bytes + 255) & ~(size_t)255;
        return p;
    };
    short* wt_qkv  = (short*)alloc(2304ull * 768 * 2);
    short* wt_proj = (short*)alloc(768ull * 768 * 2);
    short* wt_fc1  = (short*)alloc(3072ull * 768 * 2);
    short* wt_fc2  = (short*)alloc(768ull * 3072 * 2);
    short* hbuf    = (short*)alloc(8192ull * 768 * 2);
    short* Qb      = (short*)alloc(8192ull * 768 * 2);   // [B,NH,S,HD]
    short* Kbuf    = (short*)alloc(8192ull * 768 * 2);   // [B,NH,S,HD]
    short* Vtb     = (short*)alloc(8192ull * 768 * 2);   // [B,NH,HD,S]
    short* attnb   = (short*)alloc(8192ull * 768 * 2);   // [B,S,H]
    float* x2      = (float*)alloc(8192ull * 768 * 4);   // fp32 residual stream
    short* mfc     = Qb;  // alias: fc1 output [8192,3072] over dead Q/K/Vt/attn
    (void)ws_size; (void)in_sizes; (void)n_in; (void)out_size;

    // weight prep
    transpose_w<<<dim3(2304 / 32, 768 / 32), 256, 0, stream>>>(qkv_w, wt_qkv, 768, 2304);
    transpose_w<<<dim3(768 / 32, 768 / 32), 256, 0, stream>>>(proj_w, wt_proj, 768, 768);
    transpose_w<<<dim3(3072 / 32, 768 / 32), 256, 0, stream>>>(fc1_w, wt_fc1, 768, 3072);
    transpose_w<<<dim3(768 / 32, 3072 / 32), 256, 0, stream>>>(fc2_w, wt_fc2, 3072, 768);

    // attention sublayer
    ln_k<<<8192, 256, 0, stream>>>(x, ln1_g, ln1_b, hbuf);
    gemm_k<MODE_QKV><<<dim3(64, 18), 256, 0, stream>>>(
        hbuf, wt_qkv, qkv_b, nullptr, nullptr, nullptr, Qb, Kbuf, Vtb, 8192, 2304, 768);
    attn_k<<<1536, 256, 0, stream>>>(Qb, Kbuf, Vtb, attnb);
    gemm_k<MODE_F32RES><<<dim3(64, 6), 256, 0, stream>>>(
        attnb, wt_proj, proj_b, x, x2, nullptr, nullptr, nullptr, nullptr, 8192, 768, 768);

    // MLP sublayer
    ln_k<<<8192, 256, 0, stream>>>(x2, ln2_g, ln2_b, hbuf);
    gemm_k<MODE_GELU><<<dim3(64, 24), 256, 0, stream>>>(
        hbuf, wt_fc1, fc1_b, nullptr, nullptr, mfc, nullptr, nullptr, nullptr, 8192, 3072, 768);
    gemm_k<MODE_F32RES><<<dim3(64, 6), 256, 0, stream>>>(
        mfc, wt_fc2, fc2_b, x2, outp, nullptr, nullptr, nullptr, nullptr, 8192, 768, 3072);
}

// Round 3
// 324.427 us; speedup vs baseline: 1.1184x; 1.0616x over previous
//
#include <hip/hip_runtime.h>
#include <hip/hip_bf16.h>

// ---------------------------------------------------------------------------
// Transformer block, B=8 S=1024 H=768 NH=12 HD=64 I=3072.  fp32 in/out,
// bf16 MFMA internals.
// Round 2: GEMM engine -> 128x128 tile, BK=32, THREE LDS buffers (48KB),
// stage-2-tiles-ahead with counted s_waitcnt vmcnt(4) (never 0 in loop),
// raw s_barrier pairs per K-tile, T2 XOR swizzle on LDS reads, T5 setprio.
// ---------------------------------------------------------------------------

typedef __attribute__((ext_vector_type(8))) short bf16x8;
typedef __attribute__((ext_vector_type(4))) float f32x4;

#define MFMA16(a, b, c) __builtin_amdgcn_mfma_f32_16x16x32_bf16((a), (b), (c), 0, 0, 0)

__device__ inline short f2bf(float x) {
    __hip_bfloat16 h = __float2bfloat16(x);
    return *reinterpret_cast<short*>(&h);
}

__device__ inline void gload_lds16(const void* g, void* lds) {
    __builtin_amdgcn_global_load_lds(
        (const __attribute__((address_space(1))) unsigned int*)g,
        (__attribute__((address_space(3))) unsigned int*)lds,
        16, 0, 0);
}

// ---------------------------------------------------------------------------
// Weight prep: W fp32 [K,N] -> Wt bf16 [N,K]   (tiled transpose + cast)
// ---------------------------------------------------------------------------
__global__ __launch_bounds__(256) void transpose_w(
    const float* __restrict__ W, short* __restrict__ Wt, int K, int N) {
    __shared__ float tile[32][33];
    const int tx = threadIdx.x & 31, ty = threadIdx.x >> 5;  // ty 0..7
    const int n0 = blockIdx.x * 32, k0 = blockIdx.y * 32;
#pragma unroll
    for (int i = 0; i < 4; ++i)
        tile[ty + i * 8][tx] = W[(size_t)(k0 + ty + i * 8) * N + n0 + tx];
    __syncthreads();
#pragma unroll
    for (int i = 0; i < 4; ++i)
        Wt[(size_t)(n0 + ty + i * 8) * K + k0 + tx] = f2bf(tile[tx][ty + i * 8]);
}

// ---------------------------------------------------------------------------
// LayerNorm: fp32 [M,768] -> bf16 [M,768]   (one block per row)
// ---------------------------------------------------------------------------
__global__ __launch_bounds__(256) void ln_k(
    const float* __restrict__ x, const float* __restrict__ g,
    const float* __restrict__ b, short* __restrict__ out) {
    const int row = blockIdx.x;
    const int tid = threadIdx.x;
    const float* xr = x + (size_t)row * 768;
    float v[3];
    float s = 0.f, sq = 0.f;
#pragma unroll
    for (int i = 0; i < 3; ++i) {
        v[i] = xr[tid + i * 256];
        s += v[i];
        sq += v[i] * v[i];
    }
#pragma unroll
    for (int off = 32; off >= 1; off >>= 1) {
        s += __shfl_xor(s, off);
        sq += __shfl_xor(sq, off);
    }
    __shared__ float ss[4], ssq[4];
    const int wid = tid >> 6;
    if ((tid & 63) == 0) { ss[wid] = s; ssq[wid] = sq; }
    __syncthreads();
    s = ss[0] + ss[1] + ss[2] + ss[3];
    sq = ssq[0] + ssq[1] + ssq[2] + ssq[3];
    const float mean = s * (1.0f / 768.0f);
    const float var = sq * (1.0f / 768.0f) - mean * mean;  // biased
    const float rstd = rsqrtf(var + 1e-5f);
    short* outr = out + (size_t)row * 768;
#pragma unroll
    for (int i = 0; i < 3; ++i) {
        const int c = tid + i * 256;
        outr[c] = f2bf((v[i] - mean) * rstd * g[c] + b[c]);
    }
}

// ---------------------------------------------------------------------------
// GEMM engine:  C[M,N] = A[M,K](bf16) @ Wt[N,K]^T(bf16) + bias, fused epilogues.
// 128x128 tile, BK=32, 4 waves (2x2), wave = 64x64 out (4x4 16x16 frags).
// 3 LDS buffers; iter t: read buf t%3, stage tile t+2 into buf (t+2)%3,
// s_waitcnt vmcnt(4) (tile t+1 landed; t+2's 4 loads stay in flight),
// barrier / setprio(1)+16 MFMA+setprio(0) / barrier.
// LDS half layout [64][32] bf16, read swizzle: col16B ^= (row&3)<<4
// (write side pre-swizzles the GLOBAL source; LDS dest stays linear for
//  global_load_lds).
// ---------------------------------------------------------------------------
enum { MODE_BF16 = 0, MODE_QKV = 1, MODE_F32RES = 2, MODE_GELU = 3 };

template <int MODE>
__global__ __launch_bounds__(256) void gemm3p(
    const short* __restrict__ A, const short* __restrict__ Wt,
    const float* __restrict__ bias, const float* __restrict__ resid,
    float* __restrict__ outf, short* __restrict__ outh,
    short* __restrict__ Qo, short* __restrict__ Ko, short* __restrict__ Vto,
    int M, int N, int K) {
    __shared__ __attribute__((aligned(128))) short Al[3][4096];  // [buf][128*32]
    __shared__ __attribute__((aligned(128))) short Bl[3][4096];
    const int tid = threadIdx.x;
    const int lane = tid & 63;
    const int w = tid >> 6;          // 4 waves
    const int wm = w >> 1, wn = w & 1;
    const int m0 = blockIdx.x * 128, n0 = blockIdx.y * 128;

    f32x4 acc[4][4] = {};

    // ---- staging addresses (per-thread global src is pre-swizzled) ----
    // thread covers LDS bytes [tid*16, +16) of each half (linear dest).
    // linear half elem: r = tid>>2, c16 = (tid&3)*16 bytes; swizzled source
    // column (shorts): ((tid&3)*8) ^ (((tid>>2)&3)<<3)
    const int srow = tid >> 2;
    const int scol = ((tid & 3) * 8) ^ (((tid >> 2) & 3) << 3);
    const short* Abase = A + (size_t)(m0 + srow) * K + scol;
    const short* Bbase = Wt + (size_t)(n0 + srow) * K + scol;
    const size_t K64 = (size_t)K * 64;

    auto stageT = [&](int bb, int k0s) {
        gload_lds16(Abase + k0s,        &Al[bb][w * 512]);
        gload_lds16(Abase + K64 + k0s,  &Al[bb][2048 + w * 512]);
        gload_lds16(Bbase + k0s,        &Bl[bb][w * 512]);
        gload_lds16(Bbase + K64 + k0s,  &Bl[bb][2048 + w * 512]);
    };

    // ---- read offsets (swizzled) ----
    const int lrow = lane & 15;
    const int lcolswz = ((lane >> 4) * 16) ^ ((lane & 3) << 4);  // bytes
    const int aoff = wm * 4096 + lrow * 64 + lcolswz;  // bytes within Al[b]
    const int boff = wn * 4096 + lrow * 64 + lcolswz;

    const int NT = K >> 5;

    // prologue: stage tiles 0,1; wait tile 0; barrier
    stageT(0, 0);
    stageT(1, 32);
    asm volatile("s_waitcnt vmcnt(4)" ::: "memory");
    __builtin_amdgcn_sched_barrier(0);
    __builtin_amdgcn_s_barrier();

    int b = 0;
    for (int t = 0; t < NT; ++t) {
        bf16x8 av[4], bv[4];
        const char* Ab = (const char*)&Al[b][0];
        const char* Bb = (const char*)&Bl[b][0];
#pragma unroll
        for (int mi = 0; mi < 4; ++mi)
            av[mi] = *(const bf16x8*)(Ab + aoff + mi * 1024);
#pragma unroll
        for (int ni = 0; ni < 4; ++ni)
            bv[ni] = *(const bf16x8*)(Bb + boff + ni * 1024);

        int b2 = b + 2; if (b2 >= 3) b2 -= 3;
        if (t + 2 < NT) {
            stageT(b2, (t + 2) << 5);
            asm volatile("s_waitcnt vmcnt(4)" ::: "memory");  // tile t+1 landed
        } else if (t + 1 < NT) {
            asm volatile("s_waitcnt vmcnt(0)" ::: "memory");  // drain last prefetch
        }
        __builtin_amdgcn_sched_barrier(0);
        __builtin_amdgcn_s_barrier();

        __builtin_amdgcn_s_setprio(1);
#pragma unroll
        for (int mi = 0; mi < 4; ++mi)
#pragma unroll
            for (int ni = 0; ni < 4; ++ni)
                acc[mi][ni] = MFMA16(av[mi], bv[ni], acc[mi][ni]);
        __builtin_amdgcn_s_setprio(0);
        __builtin_amdgcn_s_barrier();

        if (++b == 3) b = 0;
    }

    // Epilogue.  C/D frag layout: col = lane&15, row = (lane>>4)*4 + r.
#pragma unroll
    for (int mi = 0; mi < 4; ++mi) {
#pragma unroll
        for (int ni = 0; ni < 4; ++ni) {
#pragma unroll
            for (int r = 0; r < 4; ++r) {
                const int row = m0 + wm * 64 + mi * 16 + (lane >> 4) * 4 + r;
                const int col = n0 + wn * 64 + ni * 16 + (lane & 15);
                float v = acc[mi][ni][r] + bias[col];
                if constexpr (MODE == MODE_BF16) {
                    outh[(size_t)row * N + col] = f2bf(v);
                } else if constexpr (MODE == MODE_GELU) {
                    const float t = v + 0.044715f * v * v * v;
                    const float gl = 0.5f * v * (1.0f + tanhf(0.7978845608028654f * t));
                    outh[(size_t)row * N + col] = f2bf(gl);
                } else if constexpr (MODE == MODE_F32RES) {
                    outf[(size_t)row * N + col] = v + resid[(size_t)row * N + col];
                } else {  // MODE_QKV: scatter into Q[B,NH,S,HD], K[B,NH,S,HD], Vt[B,NH,HD,S]
                    const int bb = row >> 10, s = row & 1023;
                    if (col < 768) {
                        const int hh = col >> 6, d = col & 63;
                        Qo[(((size_t)(bb * 12 + hh)) * 1024 + s) * 64 + d] = f2bf(v);
                    } else if (col < 1536) {
                        const int c2 = col - 768;
                        const int hh = c2 >> 6, d = c2 & 63;
                        Ko[(((size_t)(bb * 12 + hh)) * 1024 + s) * 64 + d] = f2bf(v);
                    } else {
                        const int c2 = col - 1536;
                        const int hh = c2 >> 6, d = c2 & 63;
                        Vto[(((size_t)(bb * 12 + hh)) * 64 + d) * 1024 + s] = f2bf(v);
                    }
                }
            }
        }
    }
}

// ---------------------------------------------------------------------------
// Flash attention.  Grid: B*NH*16 blocks; block = 4 waves, wave = 16 q-rows.
// K/V tiles (64 kv) staged in LDS (stride 80 shorts).  P via per-wave LDS.
// ---------------------------------------------------------------------------
__global__ __launch_bounds__(256) void attn_k(
    const short* __restrict__ Q, const short* __restrict__ Kg,
    const short* __restrict__ Vtg, short* __restrict__ out) {
    __shared__ __attribute__((aligned(128))) short Kl[64 * 80];
    __shared__ __attribute__((aligned(128))) short Vl[64 * 80];
    __shared__ __attribute__((aligned(128))) short Pl[4][16 * 80];
    const int tid = threadIdx.x, lane = tid & 63, w = tid >> 6;
    const int bid = blockIdx.x;
    const int qt = bid & 15, bh = bid >> 4;
    const int b = bh / 12, h = bh % 12;
    const int q0 = qt * 64 + w * 16;

    bf16x8 aq[2];
    const short* Qb = Q + ((size_t)bh * 1024 + q0) * 64;
#pragma unroll
    for (int kk = 0; kk < 2; ++kk)
        aq[kk] = *(const bf16x8*)&Qb[(size_t)(lane & 15) * 64 + kk * 32 + (lane >> 4) * 8];

    float m_run[4], l_run[4];
    f32x4 o[4] = {};
#pragma unroll
    for (int r = 0; r < 4; ++r) { m_run[r] = -1e30f; l_run[r] = 0.f; }

    const short* Kb = Kg + (size_t)bh * 1024 * 64;
    const short* Vb = Vtg + (size_t)bh * 64 * 1024;

    for (int kv0 = 0; kv0 < 1024; kv0 += 64) {
        for (int c = tid; c < 512; c += 256) {
            const int rr = c >> 3, pp = (c & 7) * 8;
            *(bf16x8*)&Kl[rr * 80 + pp] = *(const bf16x8*)&Kb[(size_t)(kv0 + rr) * 64 + pp];
            *(bf16x8*)&Vl[rr * 80 + pp] = *(const bf16x8*)&Vb[(size_t)rr * 1024 + kv0 + pp];
        }
        __syncthreads();

        f32x4 sc[4];
#pragma unroll
        for (int nk = 0; nk < 4; ++nk) {
            const bf16x8 kb0 = *(const bf16x8*)&Kl[(nk * 16 + (lane & 15)) * 80 + (lane >> 4) * 8];
            const bf16x8 kb1 = *(const bf16x8*)&Kl[(nk * 16 + (lane & 15)) * 80 + 32 + (lane >> 4) * 8];
            f32x4 z = {};
            z = MFMA16(aq[0], kb0, z);
            z = MFMA16(aq[1], kb1, z);
            sc[nk] = z * 0.125f;  // 1/sqrt(64)
        }

        float alpha[4], padd[4][4];
#pragma unroll
        for (int r = 0; r < 4; ++r) {
            float ml = fmaxf(fmaxf(sc[0][r], sc[1][r]), fmaxf(sc[2][r], sc[3][r]));
#pragma unroll
            for (int mk = 1; mk <= 8; mk <<= 1) ml = fmaxf(ml, __shfl_xor(ml, mk));
            const float mn = fmaxf(m_run[r], ml);
            alpha[r] = __expf(m_run[r] - mn);
            m_run[r] = mn;
            float rsum = 0.f;
#pragma unroll
            for (int nk = 0; nk < 4; ++nk) {
                padd[nk][r] = __expf(sc[nk][r] - mn);
                rsum += padd[nk][r];
            }
#pragma unroll
            for (int mk = 1; mk <= 8; mk <<= 1) rsum += __shfl_xor(rsum, mk);
            l_run[r] = l_run[r] * alpha[r] + rsum;
#pragma unroll
            for (int dn = 0; dn < 4; ++dn) o[dn][r] *= alpha[r];
        }

#pragma unroll
        for (int nk = 0; nk < 4; ++nk)
#pragma unroll
            for (int r = 0; r < 4; ++r)
                Pl[w][((lane >> 4) * 4 + r) * 80 + nk * 16 + (lane & 15)] = f2bf(padd[nk][r]);
        bf16x8 pa[2];
#pragma unroll
        for (int kk = 0; kk < 2; ++kk)
            pa[kk] = *(const bf16x8*)&Pl[w][(lane & 15) * 80 + kk * 32 + (lane >> 4) * 8];

#pragma unroll
        for (int dn = 0; dn < 4; ++dn) {
            const bf16x8 bv0 = *(const bf16x8*)&Vl[(dn * 16 + (lane & 15)) * 80 + (lane >> 4) * 8];
            const bf16x8 bv1 = *(const bf16x8*)&Vl[(dn * 16 + (lane & 15)) * 80 + 32 + (lane >> 4) * 8];
            o[dn] = MFMA16(pa[0], bv0, o[dn]);
            o[dn] = MFMA16(pa[1], bv1, o[dn]);
        }
        __syncthreads();
    }

#pragma unroll
    for (int dn = 0; dn < 4; ++dn)
#pragma unroll
        for (int r = 0; r < 4; ++r) {
            const int srow = q0 + (lane >> 4) * 4 + r;
            const float v = o[dn][r] / l_run[r];
            out[((size_t)(b * 1024) + srow) * 768 + h * 64 + dn * 16 + (lane & 15)] = f2bf(v);
        }
}

// ---------------------------------------------------------------------------
// Launch
// ---------------------------------------------------------------------------
extern "C" void kernel_launch(void* const* d_in, const int* in_sizes, int n_in,
                              void* d_out, int out_size, void* d_ws, size_t ws_size,
                              hipStream_t stream) {
    const float* x      = (const float*)d_in[0];
    const float* ln1_g  = (const float*)d_in[1];
    const float* ln1_b  = (const float*)d_in[2];
    const float* qkv_w  = (const float*)d_in[3];
    const float* qkv_b  = (const float*)d_in[4];
    const float* proj_w = (const float*)d_in[5];
    const float* proj_b = (const float*)d_in[6];
    const float* ln2_g  = (const float*)d_in[7];
    const float* ln2_b  = (const float*)d_in[8];
    const float* fc1_w  = (const float*)d_in[9];
    const float* fc1_b  = (const float*)d_in[10];
    const float* fc2_w  = (const float*)d_in[11];
    const float* fc2_b  = (const float*)d_in[12];
    float* outp = (float*)d_out;

    char* ws = (char*)d_ws;
    size_t off = 0;
    auto alloc = [&](size_t bytes) {
        char* p = ws + off;
        off = (off + bytes + 255) & ~(size_t)255;
        return p;
    };
    short* wt_qkv  = (short*)alloc(2304ull * 768 * 2);
    short* wt_proj = (short*)alloc(768ull * 768 * 2);
    short* wt_fc1  = (short*)alloc(3072ull * 768 * 2);
    short* wt_fc2  = (short*)alloc(768ull * 3072 * 2);
    short* hbuf    = (short*)alloc(8192ull * 768 * 2);
    short* Qb      = (short*)alloc(8192ull * 768 * 2);   // [B,NH,S,HD]
    short* Kbuf    = (short*)alloc(8192ull * 768 * 2);   // [B,NH,S,HD]
    short* Vtb     = (short*)alloc(8192ull * 768 * 2);   // [B,NH,HD,S]
    short* attnb   = (short*)alloc(8192ull * 768 * 2);   // [B,S,H]
    float* x2      = (float*)alloc(8192ull * 768 * 4);   // fp32 residual stream
    short* mfc     = Qb;  // alias: fc1 output [8192,3072] over dead Q/K/Vt/attn
    (void)ws_size; (void)in_sizes; (void)n_in; (void)out_size;

    // weight prep
    transpose_w<<<dim3(2304 / 32, 768 / 32), 256, 0, stream>>>(qkv_w, wt_qkv, 768, 2304);
    transpose_w<<<dim3(768 / 32, 768 / 32), 256, 0, stream>>>(proj_w, wt_proj, 768, 768);
    transpose_w<<<dim3(3072 / 32, 768 / 32), 256, 0, stream>>>(fc1_w, wt_fc1, 768, 3072);
    transpose_w<<<dim3(768 / 32, 3072 / 32), 256, 0, stream>>>(fc2_w, wt_fc2, 3072, 768);

    // attention sublayer
    ln_k<<<8192, 256, 0, stream>>>(x, ln1_g, ln1_b, hbuf);
    gemm3p<MODE_QKV><<<dim3(64, 18), 256, 0, stream>>>(
        hbuf, wt_qkv, qkv_b, nullptr, nullptr, nullptr, Qb, Kbuf, Vtb, 8192, 2304, 768);
    attn_k<<<1536, 256, 0, stream>>>(Qb, Kbuf, Vtb, attnb);
    gemm3p<MODE_F32RES><<<dim3(64, 6), 256, 0, stream>>>(
        attnb, wt_proj, proj_b, x, x2, nullptr, nullptr, nullptr, nullptr, 8192, 768, 768);

    // MLP sublayer
    ln_k<<<8192, 256, 0, stream>>>(x2, ln2_g, ln2_b, hbuf);
    gemm3p<MODE_GELU><<<dim3(64, 24), 256, 0, stream>>>(
        hbuf, wt_fc1, fc1_b, nullptr, nullptr, mfc, nullptr, nullptr, nullptr, 8192, 3072, 768);
    gemm3p<MODE_F32RES><<<dim3(64, 6), 256, 0, stream>>>(
        mfc, wt_fc2, fc2_b, x2, outp, nullptr, nullptr, nullptr, nullptr, 8192, 768, 3072);
}